// Round 1
// 847.255 us; speedup vs baseline: 1.3152x; 1.3152x over previous
//
#include <hip/hip_runtime.h>
#include <hip/hip_bf16.h>
#include <stdint.h>

using bf16 = __hip_bfloat16;
typedef __attribute__((ext_vector_type(8))) short  frag_ab;   // 8 bf16 (4 VGPRs)
typedef __attribute__((ext_vector_type(4))) float  frag_cd;   // 4 fp32

#define AS3(p)  ((__attribute__((address_space(3))) void*)(p))
#define AS1C(p) ((const __attribute__((address_space(1))) void*)(p))

static __device__ __forceinline__ float bf_to_f(unsigned short h) {
  union { unsigned u; float f; } c; c.u = ((unsigned)h) << 16; return c.f;
}
static __device__ __forceinline__ unsigned short f_to_bf(float f) {
  union { float fv; unsigned u; } c; c.fv = f;
  unsigned u = c.u + (0x7FFFu + ((c.u >> 16) & 1u));   // round-to-nearest-even
  return (unsigned short)(u >> 16);
}

// ---- transpose + cast: out[c][r] = bf16(in[r][c]); in: RxC fp32, out: CxR bf16
__global__ __launch_bounds__(256)
void transpose_cast_kernel(const float* __restrict__ in,
                           unsigned short* __restrict__ out,
                           int R, int C) {
  __shared__ float tile[64][65];
  const int t = threadIdx.x;
  const size_t c0 = (size_t)blockIdx.x * 64;
  const size_t r0 = (size_t)blockIdx.y * 64;
  const int lr = t >> 4;            // 0..15
  const int lc = (t & 15) * 4;      // 0..60
  #pragma unroll
  for (int i = 0; i < 64; i += 16) {
    const float4 v = *(const float4*)(in + (r0 + lr + i) * C + (c0 + lc));
    tile[lr + i][lc]     = v.x;
    tile[lr + i][lc + 1] = v.y;
    tile[lr + i][lc + 2] = v.z;
    tile[lr + i][lc + 3] = v.w;
  }
  __syncthreads();
  const int oc = t >> 3;            // 0..31
  const int orr = (t & 7) * 8;      // 0..56
  #pragma unroll
  for (int p = 0; p < 2; ++p) {
    const int c = oc + p * 32;
    frag_ab o;
    #pragma unroll
    for (int j = 0; j < 8; ++j) o[j] = (short)f_to_bf(tile[orr + j][c]);
    *(frag_ab*)(out + (c0 + c) * R + (r0 + orr)) = o;
  }
}

// ---- elementwise cast fp32 -> bf16, 8 elems/thread
__global__ void cast_kernel(const float* __restrict__ in, unsigned short* __restrict__ out) {
  const size_t i = ((size_t)blockIdx.x * 256 + threadIdx.x) * 8;
  const float4 a = *(const float4*)(in + i);
  const float4 b = *(const float4*)(in + i + 4);
  frag_ab o;
  o[0] = (short)f_to_bf(a.x); o[1] = (short)f_to_bf(a.y);
  o[2] = (short)f_to_bf(a.z); o[3] = (short)f_to_bf(a.w);
  o[4] = (short)f_to_bf(b.x); o[5] = (short)f_to_bf(b.y);
  o[6] = (short)f_to_bf(b.z); o[7] = (short)f_to_bf(b.w);
  *(frag_ab*)(out + i) = o;
}

// ============================================================================
// 256x256 tile, BK=64, 8 waves (2m x 4n), 8-phase schedule (T1+T2+T3+T4+T5).
// C[m][n] = scale * sum_k A[m][k]*B[n][k];  A: MxK bf16, B: NxK bf16.
//
// Per-wave output 128x64 with SPLIT footprint:
//   A rows: wm*64+[0,64) (mh0, in A-half0) and 128+wm*64+[0,64) (mh1, A-half1)
//   B rows: wn*32+[0,32) (nh0, B-half0) and 128+wn*32+[0,32) (nh1, B-half1)
// so each phase (one C-quadrant, 16 MFMA) reads exactly one A-half + one
// B-half, and half-tile regions die progressively:
//   buf0: Ah0 after ph1, Bh1 after ph2, Ah1 after ph3, Bh0 after ph1 (b0 in
//   regs through ph4); buf1 mirrored at ph5..8.
// Stage slots (1 half-tile = 2 x global_load_lds dwordx4 per thread):
//   S1:Ah1(T+1)  S2:Bh0(T+1)  S3:Ah0(T+2) S4:Bh1(T+2) S5:Ah1(T+2) S6:Bh0(T+2)
//   S7:Ah0(T+3)  S8:Bh1(T+3)   -- every write lands in a dead region.
// Counted waits: s_waitcnt vmcnt(4) at ph4/ph8 only => 2 half-tiles stay in
// flight across barriers; paper-verified landing: ph5..7 need <=S2 (covered by
// ph4 wait), next ph1..3 need <=S6 (covered by ph8 wait).
// LDS: linear dest for global_load_lds; global source pre-swizzled with the
// same 2-bit XOR per 32-k sub-block the reads use (rule #21, 0 conflicts).
// ============================================================================
template <bool OUT_BF16>
__global__ __launch_bounds__(512)
void gemm256_kernel(const bf16* __restrict__ A, const bf16* __restrict__ B,
                    void* __restrict__ Cv, int N, int K, float scale,
                    int nbx, int nby) {
  // [buf][half][128 rows x 64 k] per operand -> 64 KiB each, 128 KiB total
  __shared__ __align__(16) bf16 sA[2][2][128 * 64];
  __shared__ __align__(16) bf16 sB[2][2][128 * 64];

  const int t    = threadIdx.x;
  const int lane = t & 63;
  const int wv   = t >> 6;           // 0..7
  const int wm   = wv >> 2;          // 0..1
  const int wn   = wv & 3;           // 0..3

  // ---- block swizzle (bijective): XCD-contiguous, then group-m(4)
  const int nb  = nbx * nby;
  const int bid = blockIdx.x;
  const int u   = (bid & 7) * (nb >> 3) + (bid >> 3);
  const int GM = 4;
  const int width = GM * nbx;
  const int gid = u / width;
  const int pm  = gid * GM + (u % GM);
  const int pn  = (u % width) / GM;
  const size_t bm = (size_t)pm * 256;
  const size_t bn = (size_t)pn * 256;

  // ---- staging addressing: thread t owns 16B chunks p=t and p=512+t of each
  // half-tile. LDS chunk (r = p>>3, cl = p&7) receives global chunk
  // cg = (cl&4) | ((cl&3) ^ ((r>>1)&3))  [inverse == forward, XOR involution;
  // r and r+64 share the swizzle bits so both loads share cg]
  const int r0 = t >> 3;             // 0..63
  const int cl = t & 7;
  const int cg = (cl & 4) | ((cl & 3) ^ ((r0 >> 1) & 3));
  const bf16* gA = A + (bm + (size_t)r0) * K + cg * 8;
  const bf16* gB = B + (bn + (size_t)r0) * K + cg * 8;
  const size_t hstep = (size_t)128 * K;   // half stride (rows)
  const size_t lstep = (size_t)64  * K;   // second-load stride (rows)

  // ---- fragment read addressing (16x16x32 layout: lane=(mf,quad) holds
  // row mf, k-chunk quad; swizzled chunk = kk*4 + (quad ^ ((mf>>1)&3)))
  const int mf   = lane & 15;
  const int quad = lane >> 4;
  const int cswz = quad ^ ((mf >> 1) & 3);
  const int aoff = (wm * 64 + mf) * 64 + cswz * 8;
  const int boff = (wn * 32 + mf) * 64 + cswz * 8;

  frag_cd acc[8][4];
  #pragma unroll
  for (int i = 0; i < 8; ++i)
    #pragma unroll
    for (int j = 0; j < 4; ++j)
      acc[i][j] = (frag_cd){0.f, 0.f, 0.f, 0.f};

  frag_ab ar[8];   // current mh A frags [mi*2+kk]
  frag_ab b0[4];   // nh0 B frags [ni*2+kk], live ph1->ph4
  frag_ab b1[4];   // nh1 B frags, live ph2->ph3

#define STG(arr, g, bufi, half, kt) do {                                          \
    __builtin_amdgcn_global_load_lds(AS1C((g) + (half) * hstep + (kt)),           \
                                     AS3(&arr[bufi][half][t * 8]), 16, 0, 0);     \
    __builtin_amdgcn_global_load_lds(AS1C((g) + (half) * hstep + lstep + (kt)),   \
                                     AS3(&arr[bufi][half][(512 + t) * 8]), 16, 0, 0); \
  } while (0)

#define LDA(bufi, mh) do {                                                        \
    _Pragma("unroll") for (int mi = 0; mi < 4; ++mi)                              \
      _Pragma("unroll") for (int kk = 0; kk < 2; ++kk)                            \
        ar[mi * 2 + kk] = *(const frag_ab*)(&sA[bufi][mh][0] + aoff + mi * 1024 + kk * 32); \
  } while (0)

#define LDB(dst, bufi, nh) do {                                                   \
    _Pragma("unroll") for (int ni = 0; ni < 2; ++ni)                              \
      _Pragma("unroll") for (int kk = 0; kk < 2; ++kk)                            \
        dst[ni * 2 + kk] = *(const frag_ab*)(&sB[bufi][nh][0] + boff + ni * 1024 + kk * 32); \
  } while (0)

#define MM(mh, nh, bb) do {                                                       \
    __builtin_amdgcn_s_setprio(1);                                                \
    _Pragma("unroll") for (int mi = 0; mi < 4; ++mi)                              \
      _Pragma("unroll") for (int ni = 0; ni < 2; ++ni)                            \
        _Pragma("unroll") for (int kk = 0; kk < 2; ++kk)                          \
          acc[(mh) * 4 + mi][(nh) * 2 + ni] = __builtin_amdgcn_mfma_f32_16x16x32_bf16( \
              ar[mi * 2 + kk], bb[ni * 2 + kk], acc[(mh) * 4 + mi][(nh) * 2 + ni], 0, 0, 0); \
    __builtin_amdgcn_s_setprio(0);                                                \
  } while (0)

#define BAR() do { asm volatile("" ::: "memory");                                 \
                   __builtin_amdgcn_s_barrier();                                  \
                   asm volatile("" ::: "memory"); } while (0)
#define WAIT4() asm volatile("s_waitcnt vmcnt(4)" ::: "memory")

  // ---- prologue: all of tile 0 (buf0) + {Ah0,Bh1} of tile 1 (buf1)
  STG(sA, gA, 0, 0, 0);
  STG(sB, gB, 0, 0, 0);
  STG(sA, gA, 0, 1, 0);
  STG(sB, gB, 0, 1, 0);
  STG(sA, gA, 1, 0, 64);
  STG(sB, gB, 1, 1, 64);
  WAIT4();               // tile 0 landed; 2 half-tiles of tile 1 in flight
  BAR();

  const int NIT = K >> 7;            // 2 K-tiles (BK=64) per iteration
  for (int i = 0; i < NIT; ++i) {
    const int k1 = i * 128 + 64;                 // tile T+1 (always real)
    const int last = (i == NIT - 1);
    const int k2 = last ? 0 : i * 128 + 128;     // tile T+2 (garbage-clamped)
    const int k3 = last ? 0 : i * 128 + 192;     // tile T+3 (garbage-clamped)

    // phase 1: quadrant (mh0, nh0) of buf0
    LDA(0, 0); LDB(b0, 0, 0);                    // 12 ds_read_b128
    STG(sA, gA, 1, 1, k1);                       // S1: Ah1(T+1)
    BAR(); MM(0, 0, b0); BAR();
    // phase 2: (mh0, nh1)
    LDB(b1, 0, 1);                               // 4 ds_read_b128
    STG(sB, gB, 1, 0, k1);                       // S2: Bh0(T+1)
    BAR(); MM(0, 1, b1); BAR();
    // phase 3: (mh1, nh1)
    LDA(0, 1);                                   // 8 ds_read_b128
    STG(sA, gA, 0, 0, k2);                       // S3: Ah0(T+2) [Ah0 dead]
    BAR(); MM(1, 1, b1); BAR();
    // phase 4: (mh1, nh0)  -- b0/ar already in regs
    STG(sB, gB, 0, 1, k2);                       // S4: Bh1(T+2) [Bh1 dead]
    BAR(); MM(1, 0, b0);
    WAIT4(); BAR();                              // <=S2 landed -> buf1 ready
    // phase 5: (mh0, nh0) of buf1
    LDA(1, 0); LDB(b0, 1, 0);
    STG(sA, gA, 0, 1, k2);                       // S5: Ah1(T+2) [Ah1 dead]
    BAR(); MM(0, 0, b0); BAR();
    // phase 6: (mh0, nh1)
    LDB(b1, 1, 1);
    STG(sB, gB, 0, 0, k2);                       // S6: Bh0(T+2) [Bh0 dead]
    BAR(); MM(0, 1, b1); BAR();
    // phase 7: (mh1, nh1)
    LDA(1, 1);
    STG(sA, gA, 1, 0, k3);                       // S7: Ah0(T+3)
    BAR(); MM(1, 1, b1); BAR();
    // phase 8: (mh1, nh0)
    STG(sB, gB, 1, 1, k3);                       // S8: Bh1(T+3)
    BAR(); MM(1, 0, b0);
    WAIT4(); BAR();                              // <=S6 landed -> buf0 ready
  }

#undef STG
#undef LDA
#undef LDB
#undef MM
#undef BAR
#undef WAIT4

  // ---- epilogue. C/D layout: col = lane&15, row = (lane>>4)*4 + reg
  #pragma unroll
  for (int m8 = 0; m8 < 8; ++m8) {
    const int mh = m8 >> 2, mi = m8 & 3;
    const size_t mbase = bm + mh * 128 + wm * 64 + mi * 16 + quad * 4;
    #pragma unroll
    for (int n4 = 0; n4 < 4; ++n4) {
      const int nh = n4 >> 1, ni = n4 & 1;
      const size_t n = bn + nh * 128 + wn * 32 + ni * 16 + mf;
      #pragma unroll
      for (int r = 0; r < 4; ++r) {
        const float v = acc[m8][n4][r] * scale;
        const size_t idx = (mbase + r) * (size_t)N + n;
        if (OUT_BF16) ((unsigned short*)Cv)[idx] = f_to_bf(v);
        else          ((float*)Cv)[idx] = v;
      }
    }
  }
}

// ---- in-place row softmax over 8192 bf16 cols; one block (256 thr) per row
__global__ __launch_bounds__(256)
void softmax_kernel(unsigned short* __restrict__ S) {
  unsigned short* row = S + (size_t)blockIdx.x * 8192;
  const int tid = threadIdx.x;
  const int wv = tid >> 6, ln = tid & 63;
  __shared__ float red[8];

  float x[32];
  #pragma unroll
  for (int c = 0; c < 4; ++c) {
    frag_ab v = *(const frag_ab*)(row + c * 2048 + tid * 8);
    #pragma unroll
    for (int j = 0; j < 8; ++j) x[c * 8 + j] = bf_to_f((unsigned short)v[j]);
  }
  float mx = x[0];
  #pragma unroll
  for (int i = 1; i < 32; ++i) mx = fmaxf(mx, x[i]);
  #pragma unroll
  for (int off = 32; off >= 1; off >>= 1) mx = fmaxf(mx, __shfl_xor(mx, off, 64));
  if (ln == 0) red[wv] = mx;
  __syncthreads();
  mx = fmaxf(fmaxf(red[0], red[1]), fmaxf(red[2], red[3]));

  float s = 0.f;
  #pragma unroll
  for (int i = 0; i < 32; ++i) { x[i] = __expf(x[i] - mx); s += x[i]; }
  #pragma unroll
  for (int off = 32; off >= 1; off >>= 1) s += __shfl_xor(s, off, 64);
  if (ln == 0) red[4 + wv] = s;
  __syncthreads();
  const float inv = 1.f / ((red[4] + red[5]) + (red[6] + red[7]));

  #pragma unroll
  for (int c = 0; c < 4; ++c) {
    frag_ab o;
    #pragma unroll
    for (int j = 0; j < 8; ++j) o[j] = (short)f_to_bf(x[c * 8 + j] * inv);
    *(frag_ab*)(row + c * 2048 + tid * 8) = o;
  }
}

extern "C" void kernel_launch(void* const* d_in, const int* in_sizes, int n_in,
                              void* d_out, int out_size, void* d_ws, size_t ws_size,
                              hipStream_t stream) {
  const float* Q  = (const float*)d_in[0];  // (N=4096, QD=4096)
  const float* Km = (const float*)d_in[1];  // (N=4096, M=8192)
  const float* V  = (const float*)d_in[2];  // (VD=4096, M=8192)
  float* O = (float*)d_out;                 // (QD, VD) fp32

  const int Nc = 4096;   // contraction dim of gemm1 (rows of Q/K)
  const int QD = 4096;   // q_dim
  const int M  = 8192;   // keys
  const int VD = 4096;   // v_dim

  bf16* Qt = (bf16*)d_ws;                   // QD x Nc
  bf16* Kt = Qt + (size_t)QD * Nc;          // M  x Nc
  bf16* Vb = Kt + (size_t)M * Nc;           // VD x M
  bf16* Sb = Vb + (size_t)VD * M;           // QD x M (softmax in-place)

  transpose_cast_kernel<<<dim3(QD / 64, Nc / 64), 256, 0, stream>>>(
      Q, (unsigned short*)Qt, Nc, QD);
  transpose_cast_kernel<<<dim3(M / 64, Nc / 64), 256, 0, stream>>>(
      Km, (unsigned short*)Kt, Nc, M);
  cast_kernel<<<(int)(((size_t)VD * M) / (256 * 8)), 256, 0, stream>>>(
      V, (unsigned short*)Vb);

  // S = (Qt @ Kt^T)/64 : (QD, M) bf16
  gemm256_kernel<true><<<(M / 256) * (QD / 256), 512, 0, stream>>>(
      Qt, Kt, (void*)Sb, M, Nc, 0.015625f, M / 256, QD / 256);
  // P = softmax(S) in-place
  softmax_kernel<<<QD, 256, 0, stream>>>((unsigned short*)Sb);
  // O = P @ Vb^T : (QD, VD) fp32
  gemm256_kernel<false><<<(VD / 256) * (QD / 256), 512, 0, stream>>>(
      Sb, Vb, (void*)O, VD, M, 1.0f, VD / 256, QD / 256);
}

// Round 2
// 791.450 us; speedup vs baseline: 1.4079x; 1.0705x over previous
//
#include <hip/hip_runtime.h>
#include <hip/hip_bf16.h>
#include <stdint.h>

using bf16 = __hip_bfloat16;
typedef __attribute__((ext_vector_type(8))) short  frag_ab;   // 8 bf16 (4 VGPRs)
typedef __attribute__((ext_vector_type(4))) float  frag_cd;   // 4 fp32

#define AS3(p)  ((__attribute__((address_space(3))) void*)(p))
#define AS1C(p) ((const __attribute__((address_space(1))) void*)(p))

static __device__ __forceinline__ float bf_to_f(unsigned short h) {
  union { unsigned u; float f; } c; c.u = ((unsigned)h) << 16; return c.f;
}
static __device__ __forceinline__ unsigned short f_to_bf(float f) {
  union { float fv; unsigned u; } c; c.fv = f;
  unsigned u = c.u + (0x7FFFu + ((c.u >> 16) & 1u));   // round-to-nearest-even
  return (unsigned short)(u >> 16);
}

// ---- transpose + cast: out[c][r] = bf16(in[r][c]); in: RxC fp32, out: CxR bf16
__global__ __launch_bounds__(256)
void transpose_cast_kernel(const float* __restrict__ in,
                           unsigned short* __restrict__ out,
                           int R, int C) {
  __shared__ float tile[64][65];
  const int t = threadIdx.x;
  const size_t c0 = (size_t)blockIdx.x * 64;
  const size_t r0 = (size_t)blockIdx.y * 64;
  const int lr = t >> 4;            // 0..15
  const int lc = (t & 15) * 4;      // 0..60
  #pragma unroll
  for (int i = 0; i < 64; i += 16) {
    const float4 v = *(const float4*)(in + (r0 + lr + i) * C + (c0 + lc));
    tile[lr + i][lc]     = v.x;
    tile[lr + i][lc + 1] = v.y;
    tile[lr + i][lc + 2] = v.z;
    tile[lr + i][lc + 3] = v.w;
  }
  __syncthreads();
  const int oc = t >> 3;            // 0..31
  const int orr = (t & 7) * 8;      // 0..56
  #pragma unroll
  for (int p = 0; p < 2; ++p) {
    const int c = oc + p * 32;
    frag_ab o;
    #pragma unroll
    for (int j = 0; j < 8; ++j) o[j] = (short)f_to_bf(tile[orr + j][c]);
    *(frag_ab*)(out + (c0 + c) * R + (r0 + orr)) = o;
  }
}

// ---- elementwise cast fp32 -> bf16, 8 elems/thread
__global__ void cast_kernel(const float* __restrict__ in, unsigned short* __restrict__ out) {
  const size_t i = ((size_t)blockIdx.x * 256 + threadIdx.x) * 8;
  const float4 a = *(const float4*)(in + i);
  const float4 b = *(const float4*)(in + i + 4);
  frag_ab o;
  o[0] = (short)f_to_bf(a.x); o[1] = (short)f_to_bf(a.y);
  o[2] = (short)f_to_bf(a.z); o[3] = (short)f_to_bf(a.w);
  o[4] = (short)f_to_bf(b.x); o[5] = (short)f_to_bf(b.y);
  o[6] = (short)f_to_bf(b.z); o[7] = (short)f_to_bf(b.w);
  *(frag_ab*)(out + i) = o;
}

// ============================================================================
// 256x256 tile, BK=64, 8 waves (2m x 4n), 8-phase schedule (T1+T2+T3+T4+T5).
// C[m][n] = scale * sum_k A[m][k]*B[n][k];  A: MxK bf16, B: NxK bf16.
//
// Per-wave output 128x64 with SPLIT footprint:
//   A rows: wm*64+[0,64) (mh0, A-half0) and 128+wm*64+[0,64) (mh1, A-half1)
//   B rows: wn*32+[0,32) (nh0, B-half0) and 128+wn*32+[0,32) (nh1, B-half1)
// Each phase (one C-quadrant, 16 MFMA) reads one A-half + one B-half; regions
// die progressively so each phase's single half-tile stage lands dead space.
// Counted waits: s_waitcnt vmcnt(4) at ph4/ph8 only (2 half-tiles in flight).
//
// LDS bank swizzle (R2 fix): row stride is 128 B == 32 banks, so the row term
// contributes 0 to the 16B-granule index -> need the FULL 3-bit chunk XOR:
//   stored_chunk = logical_chunk ^ (row & 7),  logical = kk*4 + quad.
// For any 8 consecutive lanes (fixed quad, 8 consecutive mf) the granule
// g = (kk*4+quad) ^ (mf&7) spans all 8 values -> conflict-free ds_read_b128
// (same invariant the measured-0-conflict 128B-row kernel had via its 2-bit
// XOR + row-parity term). Staging: linear LDS dest (global_load_lds rule),
// inverse-swizzled global source cg = (t&7) ^ ((t>>3)&7); the +64-row second
// load keeps row&7 so one pointer serves both (rule #21).
// ============================================================================
template <bool OUT_BF16>
__global__ __launch_bounds__(512)
void gemm256_kernel(const bf16* __restrict__ A, const bf16* __restrict__ B,
                    void* __restrict__ Cv, int N, int K, float scale,
                    int nbx, int nby) {
  // [buf][half][128 rows x 64 k] per operand -> 64 KiB each, 128 KiB total
  __shared__ __align__(16) bf16 sA[2][2][128 * 64];
  __shared__ __align__(16) bf16 sB[2][2][128 * 64];

  const int t    = threadIdx.x;
  const int lane = t & 63;
  const int wv   = t >> 6;           // 0..7
  const int wm   = wv >> 2;          // 0..1
  const int wn   = wv & 3;           // 0..3

  // ---- block swizzle (bijective): XCD-contiguous, then group-m(4)
  const int nb  = nbx * nby;
  const int bid = blockIdx.x;
  const int u   = (bid & 7) * (nb >> 3) + (bid >> 3);
  const int GM = 4;
  const int width = GM * nbx;
  const int gid = u / width;
  const int pm  = gid * GM + (u % GM);
  const int pn  = (u % width) / GM;
  const size_t bm = (size_t)pm * 256;
  const size_t bn = (size_t)pn * 256;

  // ---- staging addressing: thread t owns 16B chunks p=t and p=512+t of each
  // half-tile. LDS chunk (row = p>>3, stored = p&7) receives global chunk
  // cg = stored ^ (row & 7)  [XOR involution; rows r and r+64 share row&7]
  const int r0 = t >> 3;             // 0..63
  const int cg = (t & 7) ^ (r0 & 7);
  const bf16* gA = A + (bm + (size_t)r0) * K + cg * 8;
  const bf16* gB = B + (bn + (size_t)r0) * K + cg * 8;
  const size_t hstep = (size_t)128 * K;   // half stride (rows)
  const size_t lstep = (size_t)64  * K;   // second-load stride (rows)

  // ---- fragment read addressing: lane (mf,quad) wants logical chunk
  // kk*4+quad of its row; stored at (kk*4+quad) ^ (mf&7). mi*16/ni*16/wm*64/
  // wn*32 are all == 0 mod 8 so row&7 == mf&7 for every fragment row.
  const int mf   = lane & 15;
  const int quad = lane >> 4;
  const int swz  = mf & 7;
  const int ck0  = ((0 * 4 + quad) ^ swz) * 8;   // kk=0 chunk offset (bf16)
  const int ck1  = ((1 * 4 + quad) ^ swz) * 8;   // kk=1
  const int aoff = (wm * 64 + mf) * 64;
  const int boff = (wn * 32 + mf) * 64;

  frag_cd acc[8][4];
  #pragma unroll
  for (int i = 0; i < 8; ++i)
    #pragma unroll
    for (int j = 0; j < 4; ++j)
      acc[i][j] = (frag_cd){0.f, 0.f, 0.f, 0.f};

  frag_ab ar[8];   // current mh A frags [mi*2+kk]
  frag_ab b0[4];   // nh0 B frags [ni*2+kk], live ph1->ph4
  frag_ab b1[4];   // nh1 B frags, live ph2->ph3

#define STG(arr, g, bufi, half, kt) do {                                          \
    __builtin_amdgcn_global_load_lds(AS1C((g) + (half) * hstep + (kt)),           \
                                     AS3(&arr[bufi][half][t * 8]), 16, 0, 0);     \
    __builtin_amdgcn_global_load_lds(AS1C((g) + (half) * hstep + lstep + (kt)),   \
                                     AS3(&arr[bufi][half][(512 + t) * 8]), 16, 0, 0); \
  } while (0)

#define LDA(bufi, mh) do {                                                        \
    _Pragma("unroll") for (int mi = 0; mi < 4; ++mi) {                            \
      ar[mi * 2 + 0] = *(const frag_ab*)(&sA[bufi][mh][0] + aoff + mi * 1024 + ck0); \
      ar[mi * 2 + 1] = *(const frag_ab*)(&sA[bufi][mh][0] + aoff + mi * 1024 + ck1); \
    } } while (0)

#define LDB(dst, bufi, nh) do {                                                   \
    _Pragma("unroll") for (int ni = 0; ni < 2; ++ni) {                            \
      dst[ni * 2 + 0] = *(const frag_ab*)(&sB[bufi][nh][0] + boff + ni * 1024 + ck0); \
      dst[ni * 2 + 1] = *(const frag_ab*)(&sB[bufi][nh][0] + boff + ni * 1024 + ck1); \
    } } while (0)

#define MM(mh, nh, bb) do {                                                       \
    __builtin_amdgcn_s_setprio(1);                                                \
    _Pragma("unroll") for (int mi = 0; mi < 4; ++mi)                              \
      _Pragma("unroll") for (int ni = 0; ni < 2; ++ni)                            \
        _Pragma("unroll") for (int kk = 0; kk < 2; ++kk)                          \
          acc[(mh) * 4 + mi][(nh) * 2 + ni] = __builtin_amdgcn_mfma_f32_16x16x32_bf16( \
              ar[mi * 2 + kk], bb[ni * 2 + kk], acc[(mh) * 4 + mi][(nh) * 2 + ni], 0, 0, 0); \
    __builtin_amdgcn_s_setprio(0);                                                \
  } while (0)

#define BAR() do { asm volatile("" ::: "memory");                                 \
                   __builtin_amdgcn_s_barrier();                                  \
                   asm volatile("" ::: "memory"); } while (0)
#define WAIT4() asm volatile("s_waitcnt vmcnt(4)" ::: "memory")

  // ---- prologue: all of tile 0 (buf0) + {Ah0,Bh1} of tile 1 (buf1)
  STG(sA, gA, 0, 0, 0);
  STG(sB, gB, 0, 0, 0);
  STG(sA, gA, 0, 1, 0);
  STG(sB, gB, 0, 1, 0);
  STG(sA, gA, 1, 0, 64);
  STG(sB, gB, 1, 1, 64);
  WAIT4();               // tile 0 landed; 2 half-tiles of tile 1 in flight
  BAR();

  const int NIT = K >> 7;            // 2 K-tiles (BK=64) per iteration
  for (int i = 0; i < NIT; ++i) {
    const int k1 = i * 128 + 64;                 // tile T+1 (always real)
    const int last = (i == NIT - 1);
    const int k2 = last ? 0 : i * 128 + 128;     // tile T+2 (garbage-clamped)
    const int k3 = last ? 0 : i * 128 + 192;     // tile T+3 (garbage-clamped)

    // phase 1: quadrant (mh0, nh0) of buf0
    LDA(0, 0); LDB(b0, 0, 0);                    // 12 ds_read_b128
    STG(sA, gA, 1, 1, k1);                       // S1: Ah1(T+1)
    BAR(); MM(0, 0, b0); BAR();
    // phase 2: (mh0, nh1)
    LDB(b1, 0, 1);                               // 4 ds_read_b128
    STG(sB, gB, 1, 0, k1);                       // S2: Bh0(T+1)
    BAR(); MM(0, 1, b1); BAR();
    // phase 3: (mh1, nh1)
    LDA(0, 1);                                   // 8 ds_read_b128
    STG(sA, gA, 0, 0, k2);                       // S3: Ah0(T+2) [Ah0 dead]
    BAR(); MM(1, 1, b1); BAR();
    // phase 4: (mh1, nh0)  -- b0/ar already in regs
    STG(sB, gB, 0, 1, k2);                       // S4: Bh1(T+2) [Bh1 dead]
    BAR(); MM(1, 0, b0);
    WAIT4(); BAR();                              // <=S2 landed -> buf1 ready
    // phase 5: (mh0, nh0) of buf1
    LDA(1, 0); LDB(b0, 1, 0);
    STG(sA, gA, 0, 1, k2);                       // S5: Ah1(T+2) [Ah1 dead]
    BAR(); MM(0, 0, b0); BAR();
    // phase 6: (mh0, nh1)
    LDB(b1, 1, 1);
    STG(sB, gB, 0, 0, k2);                       // S6: Bh0(T+2) [Bh0 dead]
    BAR(); MM(0, 1, b1); BAR();
    // phase 7: (mh1, nh1)
    LDA(1, 1);
    STG(sA, gA, 1, 0, k3);                       // S7: Ah0(T+3)
    BAR(); MM(1, 1, b1); BAR();
    // phase 8: (mh1, nh0)
    STG(sB, gB, 1, 1, k3);                       // S8: Bh1(T+3)
    BAR(); MM(1, 0, b0);
    WAIT4(); BAR();                              // <=S6 landed -> buf0 ready
  }

#undef STG
#undef LDA
#undef LDB
#undef MM
#undef BAR
#undef WAIT4

  // ---- epilogue. C/D layout: col = lane&15, row = (lane>>4)*4 + reg
  #pragma unroll
  for (int m8 = 0; m8 < 8; ++m8) {
    const int mh = m8 >> 2, mi = m8 & 3;
    const size_t mbase = bm + mh * 128 + wm * 64 + mi * 16 + quad * 4;
    #pragma unroll
    for (int n4 = 0; n4 < 4; ++n4) {
      const int nh = n4 >> 1, ni = n4 & 1;
      const size_t n = bn + nh * 128 + wn * 32 + ni * 16 + mf;
      #pragma unroll
      for (int r = 0; r < 4; ++r) {
        const float v = acc[m8][n4][r] * scale;
        const size_t idx = (mbase + r) * (size_t)N + n;
        if (OUT_BF16) ((unsigned short*)Cv)[idx] = f_to_bf(v);
        else          ((float*)Cv)[idx] = v;
      }
    }
  }
}

// ---- in-place row softmax over 8192 bf16 cols; one block (256 thr) per row
__global__ __launch_bounds__(256)
void softmax_kernel(unsigned short* __restrict__ S) {
  unsigned short* row = S + (size_t)blockIdx.x * 8192;
  const int tid = threadIdx.x;
  const int wv = tid >> 6, ln = tid & 63;
  __shared__ float red[8];

  float x[32];
  #pragma unroll
  for (int c = 0; c < 4; ++c) {
    frag_ab v = *(const frag_ab*)(row + c * 2048 + tid * 8);
    #pragma unroll
    for (int j = 0; j < 8; ++j) x[c * 8 + j] = bf_to_f((unsigned short)v[j]);
  }
  float mx = x[0];
  #pragma unroll
  for (int i = 1; i < 32; ++i) mx = fmaxf(mx, x[i]);
  #pragma unroll
  for (int off = 32; off >= 1; off >>= 1) mx = fmaxf(mx, __shfl_xor(mx, off, 64));
  if (ln == 0) red[wv] = mx;
  __syncthreads();
  mx = fmaxf(fmaxf(red[0], red[1]), fmaxf(red[2], red[3]));

  float s = 0.f;
  #pragma unroll
  for (int i = 0; i < 32; ++i) { x[i] = __expf(x[i] - mx); s += x[i]; }
  #pragma unroll
  for (int off = 32; off >= 1; off >>= 1) s += __shfl_xor(s, off, 64);
  if (ln == 0) red[4 + wv] = s;
  __syncthreads();
  const float inv = 1.f / ((red[4] + red[5]) + (red[6] + red[7]));

  #pragma unroll
  for (int c = 0; c < 4; ++c) {
    frag_ab o;
    #pragma unroll
    for (int j = 0; j < 8; ++j) o[j] = (short)f_to_bf(x[c * 8 + j] * inv);
    *(frag_ab*)(row + c * 2048 + tid * 8) = o;
  }
}

extern "C" void kernel_launch(void* const* d_in, const int* in_sizes, int n_in,
                              void* d_out, int out_size, void* d_ws, size_t ws_size,
                              hipStream_t stream) {
  const float* Q  = (const float*)d_in[0];  // (N=4096, QD=4096)
  const float* Km = (const float*)d_in[1];  // (N=4096, M=8192)
  const float* V  = (const float*)d_in[2];  // (VD=4096, M=8192)
  float* O = (float*)d_out;                 // (QD, VD) fp32

  const int Nc = 4096;   // contraction dim of gemm1 (rows of Q/K)
  const int QD = 4096;   // q_dim
  const int M  = 8192;   // keys
  const int VD = 4096;   // v_dim

  bf16* Qt = (bf16*)d_ws;                   // QD x Nc
  bf16* Kt = Qt + (size_t)QD * Nc;          // M  x Nc
  bf16* Vb = Kt + (size_t)M * Nc;           // VD x M
  bf16* Sb = Vb + (size_t)VD * M;           // QD x M (softmax in-place)

  transpose_cast_kernel<<<dim3(QD / 64, Nc / 64), 256, 0, stream>>>(
      Q, (unsigned short*)Qt, Nc, QD);
  transpose_cast_kernel<<<dim3(M / 64, Nc / 64), 256, 0, stream>>>(
      Km, (unsigned short*)Kt, Nc, M);
  cast_kernel<<<(int)(((size_t)VD * M) / (256 * 8)), 256, 0, stream>>>(
      V, (unsigned short*)Vb);

  // S = (Qt @ Kt^T)/64 : (QD, M) bf16
  gemm256_kernel<true><<<(M / 256) * (QD / 256), 512, 0, stream>>>(
      Qt, Kt, (void*)Sb, M, Nc, 0.015625f, M / 256, QD / 256);
  // P = softmax(S) in-place
  softmax_kernel<<<QD, 256, 0, stream>>>((unsigned short*)Sb);
  // O = P @ Vb^T : (QD, VD) fp32
  gemm256_kernel<false><<<(VD / 256) * (QD / 256), 512, 0, stream>>>(
      Sb, Vb, (void*)O, VD, M, 1.0f, VD / 256, QD / 256);
}